// Round 1
// baseline (2189.487 us; speedup 1.0000x reference)
//
#include <hip/hip_runtime.h>
#include <hip/hip_bf16.h>
#include <math.h>

// Problem constants
#define BATCH   2
#define SEQ     2048
#define NHEAD   16
#define HDIM    64
#define NEMBD   1024
#define C3      (3*NEMBD)
#define MROWS   (BATCH*SEQ)   // 4096

// ---------------------------------------------------------------------------
// Simple fp32 tiled GEMM: C[M,N] = A[M,K] @ B[K,N], all row-major.
// 64x64 block tile, BK=16, 256 threads, 4x4 per-thread micro-tile.
// ---------------------------------------------------------------------------
__global__ __launch_bounds__(256) void sgemm64(const float* __restrict__ A,
                                               const float* __restrict__ B,
                                               float* __restrict__ C,
                                               int M, int N, int K) {
    constexpr int BM = 64, BN = 64, BK = 16, TM = 4, TN = 4;
    __shared__ float As[BK][BM + 1];   // transposed + pad
    __shared__ float Bs[BK][BN];

    const int tid  = threadIdx.x;
    const int tcol = tid % 16;         // 0..15
    const int trow = tid / 16;         // 0..15
    const int block_row = blockIdx.y * BM;
    const int block_col = blockIdx.x * BN;

    // load mappings
    const int a_r = tid / 4;           // 0..63
    const int a_c = (tid % 4) * 4;     // 0,4,8,12
    const int b_r = tid / 16;          // 0..15
    const int b_c = (tid % 16) * 4;    // 0..60

    float acc[TM][TN] = {};

    for (int k0 = 0; k0 < K; k0 += BK) {
        float4 av = *(const float4*)&A[(size_t)(block_row + a_r) * K + k0 + a_c];
        float4 bv = *(const float4*)&B[(size_t)(k0 + b_r) * N + block_col + b_c];
        As[a_c + 0][a_r] = av.x;
        As[a_c + 1][a_r] = av.y;
        As[a_c + 2][a_r] = av.z;
        As[a_c + 3][a_r] = av.w;
        *(float4*)&Bs[b_r][b_c] = bv;
        __syncthreads();
#pragma unroll
        for (int kk = 0; kk < BK; ++kk) {
            float a[TM], b[TN];
#pragma unroll
            for (int i = 0; i < TM; ++i) a[i] = As[kk][trow * TM + i];
#pragma unroll
            for (int j = 0; j < TN; ++j) b[j] = Bs[kk][tcol * TN + j];
#pragma unroll
            for (int i = 0; i < TM; ++i)
#pragma unroll
                for (int j = 0; j < TN; ++j) acc[i][j] += a[i] * b[j];
        }
        __syncthreads();
    }

#pragma unroll
    for (int i = 0; i < TM; ++i) {
        int r = block_row + trow * TM + i;
        float4 v = make_float4(acc[i][0], acc[i][1], acc[i][2], acc[i][3]);
        *(float4*)&C[(size_t)r * N + block_col + tcol * TN] = v;
    }
}

// ---------------------------------------------------------------------------
// Flash-style causal attention with ALiBi bias (ADDED, slope*(i-j), i>=j).
// qkv layout: [B*T, 3072] rows; q at col h*64, k at 1024+h*64, v at 2048+h*64.
// One thread per query row i (per b,h). K/V tiles of 64 keys staged in LDS.
// Output: out[(b*T+i)*1024 + h*64 + d]  (t-major, ready for proj GEMM).
// ---------------------------------------------------------------------------
__global__ __launch_bounds__(256) void attn_fwd(const float* __restrict__ qkv,
                                                float* __restrict__ out) {
    __shared__ float Ks[64][HDIM];   // 16 KB
    __shared__ float Vs[64][HDIM];   // 16 KB

    const int tid = threadIdx.x;
    const int b = blockIdx.z;
    const int h = blockIdx.y;
    const int i = blockIdx.x * 256 + tid;

    const float scale = 0.125f;                       // 1/sqrt(64)
    const float slope = exp2f(-0.5f * (float)(h + 1)); // 1/2^(8*(h+1)/16)

    // Load q row into registers
    const float* qp = qkv + (size_t)(b * SEQ + i) * C3 + h * HDIM;
    float q[HDIM];
#pragma unroll
    for (int d = 0; d < HDIM; d += 4) {
        float4 v = *(const float4*)(qp + d);
        q[d] = v.x; q[d + 1] = v.y; q[d + 2] = v.z; q[d + 3] = v.w;
    }

    float O[HDIM];
#pragma unroll
    for (int d = 0; d < HDIM; ++d) O[d] = 0.f;
    float m = -INFINITY, l = 0.f;

    const int i_max = blockIdx.x * 256 + 255;   // block-uniform loop bound

    // cooperative tile-load mapping: 256 threads load 64 rows x 64 cols
    const int lr = tid / 4;            // key row 0..63
    const int lc = (tid % 4) * 16;     // col start 0,16,32,48

    for (int j0 = 0; j0 <= i_max; j0 += 64) {
        const float* kp = qkv + (size_t)(b * SEQ + j0 + lr) * C3 + NEMBD + h * HDIM + lc;
        const float* vp = kp + NEMBD;
#pragma unroll
        for (int c = 0; c < 16; c += 4) {
            *(float4*)&Ks[lr][lc + c] = *(const float4*)(kp + c);
            *(float4*)&Vs[lr][lc + c] = *(const float4*)(vp + c);
        }
        __syncthreads();

        const int jend = min(64, i - j0 + 1);   // #allowed keys (may be <=0)
        for (int jj = 0; jj < jend; ++jj) {
            float s = 0.f;
#pragma unroll
            for (int d = 0; d < HDIM; ++d) s += q[d] * Ks[jj][d];
            s = s * scale + slope * (float)(i - (j0 + jj));
            if (s > m) {
                float alpha = __expf(m - s);    // exp(-inf)=0 on first hit
                l *= alpha;
#pragma unroll
                for (int d = 0; d < HDIM; ++d) O[d] *= alpha;
                m = s;
            }
            float p = __expf(s - m);
            l += p;
#pragma unroll
            for (int d = 0; d < HDIM; ++d) O[d] += p * Vs[jj][d];
        }
        __syncthreads();
    }

    const float inv_l = 1.f / l;
    float* op = out + (size_t)(b * SEQ + i) * NEMBD + h * HDIM;
#pragma unroll
    for (int d = 0; d < HDIM; d += 4) {
        float4 v = make_float4(O[d] * inv_l, O[d + 1] * inv_l,
                               O[d + 2] * inv_l, O[d + 3] * inv_l);
        *(float4*)(op + d) = v;
    }
}

// ---------------------------------------------------------------------------
extern "C" void kernel_launch(void* const* d_in, const int* in_sizes, int n_in,
                              void* d_out, int out_size, void* d_ws, size_t ws_size,
                              hipStream_t stream) {
    const float* x      = (const float*)d_in[0];   // [4096, 1024]
    const float* w_qkv  = (const float*)d_in[1];   // [1024, 3072]
    const float* w_proj = (const float*)d_in[2];   // [1024, 1024]
    float* out = (float*)d_out;                    // [4096, 1024]

    float* qkv  = (float*)d_ws;                          // 4096*3072 floats
    float* attn = qkv + (size_t)MROWS * C3;              // 4096*1024 floats

    // 1) qkv = x @ w_qkv   [4096,1024]@[1024,3072]
    sgemm64<<<dim3(C3 / 64, MROWS / 64), 256, 0, stream>>>(x, w_qkv, qkv,
                                                           MROWS, C3, NEMBD);
    // 2) attention
    attn_fwd<<<dim3(SEQ / 256, NHEAD, BATCH), 256, 0, stream>>>(qkv, attn);
    // 3) out = attn @ w_proj  [4096,1024]@[1024,1024]
    sgemm64<<<dim3(NEMBD / 64, MROWS / 64), 256, 0, stream>>>(attn, w_proj, out,
                                                              MROWS, NEMBD, NEMBD);
}

// Round 2
// 884.005 us; speedup vs baseline: 2.4768x; 2.4768x over previous
//
#include <hip/hip_runtime.h>
#include <hip/hip_bf16.h>
#include <math.h>

// Problem constants
#define BATCH   2
#define SEQ     2048
#define NHEAD   16
#define HDIM    64
#define NEMBD   1024
#define C3      (3*NEMBD)
#define MROWS   (BATCH*SEQ)   // 4096

typedef short bf16x8 __attribute__((ext_vector_type(8)));
typedef float f32x4  __attribute__((ext_vector_type(4)));

static __device__ __forceinline__ short f2bf(float x) {
    union { __hip_bfloat16 h; short s; } u;
    u.h = __float2bfloat16(x);
    return u.s;
}

// Load 8 consecutive fp32 and convert to a bf16x8 MFMA fragment.
static __device__ __forceinline__ bf16x8 load_frag_f32(const float* __restrict__ p) {
    float4 a = *(const float4*)p;
    float4 b = *(const float4*)(p + 4);
    bf16x8 f;
    f[0] = f2bf(a.x); f[1] = f2bf(a.y); f[2] = f2bf(a.z); f[3] = f2bf(a.w);
    f[4] = f2bf(b.x); f[5] = f2bf(b.y); f[6] = f2bf(b.z); f[7] = f2bf(b.w);
    return f;
}

// ---------------------------------------------------------------------------
// Simple fp32 tiled GEMM: C[M,N] = A[M,K] @ B[K,N], all row-major. (unchanged)
// ---------------------------------------------------------------------------
__global__ __launch_bounds__(256) void sgemm64(const float* __restrict__ A,
                                               const float* __restrict__ B,
                                               float* __restrict__ C,
                                               int M, int N, int K) {
    constexpr int BM = 64, BN = 64, BK = 16, TM = 4, TN = 4;
    __shared__ float As[BK][BM + 1];
    __shared__ float Bs[BK][BN];

    const int tid  = threadIdx.x;
    const int tcol = tid % 16;
    const int trow = tid / 16;
    const int block_row = blockIdx.y * BM;
    const int block_col = blockIdx.x * BN;

    const int a_r = tid / 4;
    const int a_c = (tid % 4) * 4;
    const int b_r = tid / 16;
    const int b_c = (tid % 16) * 4;

    float acc[TM][TN] = {};

    for (int k0 = 0; k0 < K; k0 += BK) {
        float4 av = *(const float4*)&A[(size_t)(block_row + a_r) * K + k0 + a_c];
        float4 bv = *(const float4*)&B[(size_t)(k0 + b_r) * N + block_col + b_c];
        As[a_c + 0][a_r] = av.x;
        As[a_c + 1][a_r] = av.y;
        As[a_c + 2][a_r] = av.z;
        As[a_c + 3][a_r] = av.w;
        *(float4*)&Bs[b_r][b_c] = bv;
        __syncthreads();
#pragma unroll
        for (int kk = 0; kk < BK; ++kk) {
            float a[TM], b[TN];
#pragma unroll
            for (int i = 0; i < TM; ++i) a[i] = As[kk][trow * TM + i];
#pragma unroll
            for (int j = 0; j < TN; ++j) b[j] = Bs[kk][tcol * TN + j];
#pragma unroll
            for (int i = 0; i < TM; ++i)
#pragma unroll
                for (int j = 0; j < TN; ++j) acc[i][j] += a[i] * b[j];
        }
        __syncthreads();
    }

#pragma unroll
    for (int i = 0; i < TM; ++i) {
        int r = block_row + trow * TM + i;
        float4 v = make_float4(acc[i][0], acc[i][1], acc[i][2], acc[i][3]);
        *(float4*)&C[(size_t)r * N + block_col + tcol * TN] = v;
    }
}

// ---------------------------------------------------------------------------
// V transpose + bf16 convert: qkv fp32 [B*T, 3072] (v at col 2048+h*64)
//   -> vt bf16 [B*H][64 dims][2048 keys]
// Block: (t-tile 64) x head x batch; 256 threads; LDS-tiled transpose.
// ---------------------------------------------------------------------------
__global__ __launch_bounds__(256) void conv_vt(const float* __restrict__ qkv,
                                               __hip_bfloat16* __restrict__ vt) {
    __shared__ short tile[64][66];   // bf16 tile, padded row (132B) -> no bank conflicts
    const int b = blockIdx.z, h = blockIdx.y, t0 = blockIdx.x * 64;
    const int tt = threadIdx.x / 4;
    const int c0 = (threadIdx.x % 4) * 16;

    const float* src = qkv + (size_t)(b * SEQ + t0 + tt) * C3 + 2 * NEMBD + h * HDIM + c0;
#pragma unroll
    for (int c = 0; c < 16; c += 4) {
        float4 v = *(const float4*)(src + c);
        tile[tt][c0 + c + 0] = f2bf(v.x);
        tile[tt][c0 + c + 1] = f2bf(v.y);
        tile[tt][c0 + c + 2] = f2bf(v.z);
        tile[tt][c0 + c + 3] = f2bf(v.w);
    }
    __syncthreads();

    const int d = threadIdx.x / 4;           // output row (dim)
    const int tp = (threadIdx.x % 4) * 16;   // key chunk
    bf16x8 o0, o1;
#pragma unroll
    for (int k = 0; k < 8; ++k) o0[k] = tile[tp + k][d];
#pragma unroll
    for (int k = 0; k < 8; ++k) o1[k] = tile[tp + 8 + k][d];
    __hip_bfloat16* dst = vt + ((size_t)(b * NHEAD + h) * HDIM + d) * SEQ + t0 + tp;
    *(bf16x8*)dst       = o0;
    *(bf16x8*)(dst + 8) = o1;
}

// ---------------------------------------------------------------------------
// MFMA flash attention with ALiBi (+slope*(i-j)) and causal mask.
// One wave per 16-query tile; 32-key tiles; online softmax.
// Q/K read as fp32 from qkv (convert in-register); V read as bf16 from vt.
// Output: attn[(b*T+i)*1024 + h*64 + d] fp32 (t-major for proj GEMM).
// mfma_f32_16x16x32_bf16 layouts (guide-verified):
//   A: lane holds A[m=lane&15][k=quad*8+j], j=0..7
//   B: lane holds B[k=quad*8+j][n=lane&15]
//   C/D: lane holds D[row=quad*4+r][col=lane&15], r=0..3
// ---------------------------------------------------------------------------
__global__ __launch_bounds__(256) void attn_mfma(const float* __restrict__ qkv,
                                                 const __hip_bfloat16* __restrict__ vt,
                                                 float* __restrict__ out) {
    __shared__ short P_lds[4][16 * 32];   // per-wave P tile (bf16), 1 KB each

    const int wave = threadIdx.x >> 6;
    const int lane = threadIdx.x & 63;
    const int quad = lane >> 4;
    const int col  = lane & 15;
    const int b = blockIdx.z, h = blockIdx.y;

    // balance: pair low-work and high-work tiles in consecutive blocks
    const int nx = gridDim.x;
    const int xs = blockIdx.x;
    const int x  = (xs & 1) ? (nx - 1 - (xs >> 1)) : (xs >> 1);

    const int q0 = (x * 4 + wave) * 16;
    const float scale = 0.125f;                        // 1/sqrt(64)
    const float slope = exp2f(-0.5f * (float)(h + 1)); // 2^(-(h+1)/2)

    // Q A-fragments (dims 0..31 and 32..63), query row m = q0+col
    const float* qbase = qkv + (size_t)(b * SEQ + q0 + col) * C3 + h * HDIM;
    bf16x8 qa0 = load_frag_f32(qbase + quad * 8);
    bf16x8 qa1 = load_frag_f32(qbase + 32 + quad * 8);

    f32x4 O0 = {0,0,0,0}, O1 = {0,0,0,0}, O2 = {0,0,0,0}, O3 = {0,0,0,0};
    float m_r[4] = {-1e30f, -1e30f, -1e30f, -1e30f};
    float l_r[4] = {0.f, 0.f, 0.f, 0.f};

    const __hip_bfloat16* vtb = vt + (size_t)(b * NHEAD + h) * HDIM * SEQ;
    short* P = P_lds[wave];
    const int jmax = q0 + 15;

    for (int j0 = 0; j0 <= jmax; j0 += 32) {
        // ---- S = Q @ K^T for keys [j0, j0+32) ----
        const float* kb0 = qkv + (size_t)(b * SEQ + j0 + col) * C3 + NEMBD + h * HDIM;
        const float* kb1 = kb0 + (size_t)16 * C3;
        bf16x8 kf00 = load_frag_f32(kb0 + quad * 8);
        bf16x8 kf01 = load_frag_f32(kb0 + 32 + quad * 8);
        bf16x8 kf10 = load_frag_f32(kb1 + quad * 8);
        bf16x8 kf11 = load_frag_f32(kb1 + 32 + quad * 8);

        f32x4 S0 = {0,0,0,0}, S1 = {0,0,0,0};
        S0 = __builtin_amdgcn_mfma_f32_16x16x32_bf16(qa0, kf00, S0, 0, 0, 0);
        S0 = __builtin_amdgcn_mfma_f32_16x16x32_bf16(qa1, kf01, S0, 0, 0, 0);
        S1 = __builtin_amdgcn_mfma_f32_16x16x32_bf16(qa0, kf10, S1, 0, 0, 0);
        S1 = __builtin_amdgcn_mfma_f32_16x16x32_bf16(qa1, kf11, S1, 0, 0, 0);

        // ---- bias + causal mask + online softmax ----
        float s0[4], s1[4], tmax[4];
#pragma unroll
        for (int r = 0; r < 4; ++r) {
            const int i  = q0 + quad * 4 + r;
            const int ja = j0 + col;
            const int jb = j0 + 16 + col;
            s0[r] = (ja <= i) ? S0[r] * scale + slope * (float)(i - ja) : -1e30f;
            s1[r] = (jb <= i) ? S1[r] * scale + slope * (float)(i - jb) : -1e30f;
            tmax[r] = fmaxf(s0[r], s1[r]);
        }
#pragma unroll
        for (int off = 1; off < 16; off <<= 1) {
#pragma unroll
            for (int r = 0; r < 4; ++r)
                tmax[r] = fmaxf(tmax[r], __shfl_xor(tmax[r], off));
        }
        float p0[4], p1[4];
#pragma unroll
        for (int r = 0; r < 4; ++r) {
            const float mn    = fmaxf(m_r[r], tmax[r]);
            const float alpha = __expf(m_r[r] - mn);
            m_r[r] = mn;
            p0[r] = __expf(s0[r] - mn);
            p1[r] = __expf(s1[r] - mn);
            float ts = p0[r] + p1[r];
#pragma unroll
            for (int off = 1; off < 16; off <<= 1) ts += __shfl_xor(ts, off);
            l_r[r] = l_r[r] * alpha + ts;
            O0[r] *= alpha; O1[r] *= alpha; O2[r] *= alpha; O3[r] *= alpha;
        }

        // ---- P (C-layout) -> LDS -> A-layout fragment ----
#pragma unroll
        for (int r = 0; r < 4; ++r) {
            P[(quad * 4 + r) * 32 + col]      = f2bf(p0[r]);
            P[(quad * 4 + r) * 32 + 16 + col] = f2bf(p1[r]);
        }
        __asm__ volatile("s_waitcnt lgkmcnt(0)" ::: "memory");
        bf16x8 pa = *(bf16x8*)&P[col * 32 + quad * 8];
        __asm__ volatile("" ::: "memory");   // keep read before next tile's writes

        // ---- O += P @ V  (V^T B-fragments: dim chunk c, keys j0+quad*8..+7) ----
        {
            bf16x8 vf0 = *(const bf16x8*)(vtb + (size_t)(0 * 16 + col) * SEQ + j0 + quad * 8);
            bf16x8 vf1 = *(const bf16x8*)(vtb + (size_t)(1 * 16 + col) * SEQ + j0 + quad * 8);
            bf16x8 vf2 = *(const bf16x8*)(vtb + (size_t)(2 * 16 + col) * SEQ + j0 + quad * 8);
            bf16x8 vf3 = *(const bf16x8*)(vtb + (size_t)(3 * 16 + col) * SEQ + j0 + quad * 8);
            O0 = __builtin_amdgcn_mfma_f32_16x16x32_bf16(pa, vf0, O0, 0, 0, 0);
            O1 = __builtin_amdgcn_mfma_f32_16x16x32_bf16(pa, vf1, O1, 0, 0, 0);
            O2 = __builtin_amdgcn_mfma_f32_16x16x32_bf16(pa, vf2, O2, 0, 0, 0);
            O3 = __builtin_amdgcn_mfma_f32_16x16x32_bf16(pa, vf3, O3, 0, 0, 0);
        }
    }

    // ---- epilogue: normalize and store (t-major fp32) ----
#pragma unroll
    for (int r = 0; r < 4; ++r) {
        const float inv = 1.f / l_r[r];
        const int row = q0 + quad * 4 + r;
        float* op = out + (size_t)(b * SEQ + row) * NEMBD + h * HDIM;
        op[col]      = O0[r] * inv;
        op[16 + col] = O1[r] * inv;
        op[32 + col] = O2[r] * inv;
        op[48 + col] = O3[r] * inv;
    }
}

// ---------------------------------------------------------------------------
extern "C" void kernel_launch(void* const* d_in, const int* in_sizes, int n_in,
                              void* d_out, int out_size, void* d_ws, size_t ws_size,
                              hipStream_t stream) {
    const float* x      = (const float*)d_in[0];   // [4096, 1024]
    const float* w_qkv  = (const float*)d_in[1];   // [1024, 3072]
    const float* w_proj = (const float*)d_in[2];   // [1024, 1024]
    float* out = (float*)d_out;                    // [4096, 1024]

    float* qkv  = (float*)d_ws;                    // 4096*3072 fp32
    float* attn = qkv + (size_t)MROWS * C3;        // 4096*1024 fp32

    // vt (bf16 V^T, 8.4 MB) lives in d_out (16.8 MB) — free until proj writes it
    __hip_bfloat16* vt = (__hip_bfloat16*)d_out;

    // 1) qkv = x @ w_qkv
    sgemm64<<<dim3(C3 / 64, MROWS / 64), 256, 0, stream>>>(x, w_qkv, qkv,
                                                           MROWS, C3, NEMBD);
    // 2) V -> bf16 V^T
    conv_vt<<<dim3(SEQ / 64, NHEAD, BATCH), 256, 0, stream>>>(qkv, vt);
    // 3) MFMA flash attention
    attn_mfma<<<dim3(SEQ / 64, NHEAD, BATCH), 256, 0, stream>>>(qkv, vt, attn);
    // 4) out = attn @ w_proj
    sgemm64<<<dim3(NEMBD / 64, MROWS / 64), 256, 0, stream>>>(attn, w_proj, out,
                                                              MROWS, NEMBD, NEMBD);
}

// Round 3
// 370.839 us; speedup vs baseline: 5.9041x; 2.3838x over previous
//
#include <hip/hip_runtime.h>
#include <hip/hip_bf16.h>
#include <math.h>

// Problem constants
#define BATCH   2
#define SEQ     2048
#define NHEAD   16
#define HDIM    64
#define NEMBD   1024
#define C3      (3*NEMBD)
#define MROWS   (BATCH*SEQ)   // 4096

typedef short bf16x8 __attribute__((ext_vector_type(8)));
typedef float f32x4  __attribute__((ext_vector_type(4)));

static __device__ __forceinline__ short f2bf(float x) {
    union { __hip_bfloat16 h; short s; } u;
    u.h = __float2bfloat16(x);
    return u.s;
}

static __device__ __forceinline__ void stc(float* p, float v) { *p = v; }
static __device__ __forceinline__ void stc(short* p, float v) { *p = f2bf(v); }

// async global->LDS, 16B per lane. LDS dest = wave-uniform base + lane*16.
static __device__ __forceinline__ void gl_lds16(const short* g, short* lds_base) {
    __builtin_amdgcn_global_load_lds(
        (const __attribute__((address_space(1))) unsigned int*)g,
        (__attribute__((address_space(3))) unsigned int*)lds_base,
        16, 0, 0);
}

// ---------------------------------------------------------------------------
// Elementwise fp32 -> bf16 convert (8 elems/thread).
// ---------------------------------------------------------------------------
__global__ __launch_bounds__(256) void conv_x(const float* __restrict__ in,
                                              short* __restrict__ out, int n) {
    const int i = (blockIdx.x * 256 + threadIdx.x) * 8;
    if (i >= n) return;
    float4 a = *(const float4*)(in + i);
    float4 b = *(const float4*)(in + i + 4);
    bf16x8 o;
    o[0] = f2bf(a.x); o[1] = f2bf(a.y); o[2] = f2bf(a.z); o[3] = f2bf(a.w);
    o[4] = f2bf(b.x); o[5] = f2bf(b.y); o[6] = f2bf(b.z); o[7] = f2bf(b.w);
    *(bf16x8*)(out + i) = o;
}

// ---------------------------------------------------------------------------
// Weight transpose + convert: in [K,N] fp32 row-major -> out [N,K] bf16.
// 64x64 LDS tile, 256 threads.
// ---------------------------------------------------------------------------
__global__ __launch_bounds__(256) void conv_wt(const float* __restrict__ in,
                                               short* __restrict__ out,
                                               int K, int N) {
    __shared__ short tile[64][66];   // padded -> conflict-free transpose
    const int kt = blockIdx.y * 64, nt = blockIdx.x * 64;
    const int r  = threadIdx.x / 4;
    const int c0 = (threadIdx.x % 4) * 16;

    const float* src = in + (size_t)(kt + r) * N + nt + c0;
#pragma unroll
    for (int c = 0; c < 16; c += 4) {
        float4 v = *(const float4*)(src + c);
        tile[r][c0 + c + 0] = f2bf(v.x);
        tile[r][c0 + c + 1] = f2bf(v.y);
        tile[r][c0 + c + 2] = f2bf(v.z);
        tile[r][c0 + c + 3] = f2bf(v.w);
    }
    __syncthreads();

    const int nr  = threadIdx.x / 4;          // output row (n)
    const int k0c = (threadIdx.x % 4) * 16;   // k chunk
    bf16x8 o0, o1;
#pragma unroll
    for (int k = 0; k < 8; ++k) o0[k] = tile[k0c + k][nr];
#pragma unroll
    for (int k = 0; k < 8; ++k) o1[k] = tile[k0c + 8 + k][nr];
    short* dst = out + (size_t)(nt + nr) * K + kt + k0c;
    *(bf16x8*)dst       = o0;
    *(bf16x8*)(dst + 8) = o1;
}

// ---------------------------------------------------------------------------
// bf16 MFMA GEMM (m97 structure): C[M,N] = A[M,K] @ B[K,N],
// A bf16 [M,K] row-major, BT bf16 [N,K] row-major (pre-transposed B).
// 128x128 block tile, BK=32, 256 threads (4 waves, 64x64 quadrant each,
// 4x4 acc tiles of mfma_f32_16x16x32_bf16), global_load_lds width=16.
// ---------------------------------------------------------------------------
template <typename OT>
__global__ __launch_bounds__(256) void gemm_bt(const short* __restrict__ A,
                                               const short* __restrict__ BT,
                                               OT* __restrict__ C,
                                               int M, int N, int K) {
    __shared__ short As[128 * 32];   // [row][k] contiguous, 8 KB
    __shared__ short Bs[128 * 32];   // [n][k] contiguous, 8 KB

    const int tid  = threadIdx.x;
    const int wave = tid >> 6;
    const int lane = tid & 63;
    const int quad = lane >> 4;
    const int col  = lane & 15;
    const int m0 = blockIdx.y * 128;
    const int n0 = blockIdx.x * 128;
    const int mq = (wave >> 1) * 64;   // wave's m-quadrant
    const int nq = (wave & 1) * 64;    // wave's n-quadrant

    f32x4 acc[4][4] = {};

    const int cA  = wave * 64 + lane;      // staging chunk ids (8 bf16 each)
    const int cA1 = cA + 256;

    for (int k0 = 0; k0 < K; k0 += 32) {
        if (k0) __syncthreads();
        // stage A tile: rows m0..m0+128, k k0..k0+32
        gl_lds16(A + (size_t)(m0 + (cA  >> 2)) * K + k0 + (cA  & 3) * 8,
                 &As[wave * 512]);
        gl_lds16(A + (size_t)(m0 + (cA1 >> 2)) * K + k0 + (cA1 & 3) * 8,
                 &As[2048 + wave * 512]);
        // stage B tile: rows n0..n0+128 of BT
        gl_lds16(BT + (size_t)(n0 + (cA  >> 2)) * K + k0 + (cA  & 3) * 8,
                 &Bs[wave * 512]);
        gl_lds16(BT + (size_t)(n0 + (cA1 >> 2)) * K + k0 + (cA1 & 3) * 8,
                 &Bs[2048 + wave * 512]);
        __syncthreads();   // drains vmcnt before barrier -> LDS ready

        bf16x8 af[4], bfr[4];
#pragma unroll
        for (int mt = 0; mt < 4; ++mt)
            af[mt] = *(const bf16x8*)&As[(mq + mt * 16 + col) * 32 + quad * 8];
#pragma unroll
        for (int nt = 0; nt < 4; ++nt)
            bfr[nt] = *(const bf16x8*)&Bs[(nq + nt * 16 + col) * 32 + quad * 8];
#pragma unroll
        for (int mt = 0; mt < 4; ++mt)
#pragma unroll
            for (int nt = 0; nt < 4; ++nt)
                acc[mt][nt] = __builtin_amdgcn_mfma_f32_16x16x32_bf16(
                    af[mt], bfr[nt], acc[mt][nt], 0, 0, 0);
    }

    // epilogue: D[row=quad*4+r][col] per 16x16 tile
#pragma unroll
    for (int mt = 0; mt < 4; ++mt)
#pragma unroll
        for (int r = 0; r < 4; ++r) {
            const int row = m0 + mq + mt * 16 + quad * 4 + r;
            OT* cp = C + (size_t)row * N + n0 + nq + col;
#pragma unroll
            for (int nt = 0; nt < 4; ++nt)
                stc(cp + nt * 16, acc[mt][nt][r]);
        }
}

// ---------------------------------------------------------------------------
// V transpose: qkvb bf16 [B*T, 3072] (v at col 2048+h*64)
//   -> vt bf16 [B*H][64 dims][2048 keys]
// ---------------------------------------------------------------------------
__global__ __launch_bounds__(256) void conv_vt(const short* __restrict__ qkvb,
                                               short* __restrict__ vt) {
    __shared__ short tile[64][66];
    const int b = blockIdx.z, h = blockIdx.y, t0 = blockIdx.x * 64;
    const int tt = threadIdx.x / 4;
    const int c0 = (threadIdx.x % 4) * 16;

    const short* src = qkvb + (size_t)(b * SEQ + t0 + tt) * C3 + 2 * NEMBD + h * HDIM + c0;
    bf16x8 v0 = *(const bf16x8*)src;
    bf16x8 v1 = *(const bf16x8*)(src + 8);
#pragma unroll
    for (int k = 0; k < 8; ++k) tile[tt][c0 + k]     = v0[k];
#pragma unroll
    for (int k = 0; k < 8; ++k) tile[tt][c0 + 8 + k] = v1[k];
    __syncthreads();

    const int d  = threadIdx.x / 4;
    const int tp = (threadIdx.x % 4) * 16;
    bf16x8 o0, o1;
#pragma unroll
    for (int k = 0; k < 8; ++k) o0[k] = tile[tp + k][d];
#pragma unroll
    for (int k = 0; k < 8; ++k) o1[k] = tile[tp + 8 + k][d];
    short* dst = vt + ((size_t)(b * NHEAD + h) * HDIM + d) * SEQ + t0 + tp;
    *(bf16x8*)dst       = o0;
    *(bf16x8*)(dst + 8) = o1;
}

// ---------------------------------------------------------------------------
// MFMA flash attention with ALiBi (+slope*(i-j)) and causal mask.
// Q/K read bf16 directly from qkvb; V bf16 from vt; output bf16 t-major.
// ---------------------------------------------------------------------------
__global__ __launch_bounds__(256) void attn_mfma(const short* __restrict__ qkvb,
                                                 const short* __restrict__ vt,
                                                 short* __restrict__ out) {
    __shared__ short P_lds[4][16 * 32];

    const int wave = threadIdx.x >> 6;
    const int lane = threadIdx.x & 63;
    const int quad = lane >> 4;
    const int col  = lane & 15;
    const int b = blockIdx.z, h = blockIdx.y;

    // balance: pair low-work and high-work tiles
    const int nx = gridDim.x;
    const int xs = blockIdx.x;
    const int x  = (xs & 1) ? (nx - 1 - (xs >> 1)) : (xs >> 1);

    const int q0 = (x * 4 + wave) * 16;
    const float scale = 0.125f;
    const float slope = exp2f(-0.5f * (float)(h + 1));

    const short* qbase = qkvb + (size_t)(b * SEQ + q0 + col) * C3 + h * HDIM;
    bf16x8 qa0 = *(const bf16x8*)(qbase + quad * 8);
    bf16x8 qa1 = *(const bf16x8*)(qbase + 32 + quad * 8);

    f32x4 O0 = {0,0,0,0}, O1 = {0,0,0,0}, O2 = {0,0,0,0}, O3 = {0,0,0,0};
    float m_r[4] = {-1e30f, -1e30f, -1e30f, -1e30f};
    float l_r[4] = {0.f, 0.f, 0.f, 0.f};

    const short* vtb = vt + (size_t)(b * NHEAD + h) * HDIM * SEQ;
    short* P = P_lds[wave];
    const int jmax = q0 + 15;

    for (int j0 = 0; j0 <= jmax; j0 += 32) {
        const short* kb0 = qkvb + (size_t)(b * SEQ + j0 + col) * C3 + NEMBD + h * HDIM;
        const short* kb1 = kb0 + (size_t)16 * C3;
        bf16x8 kf00 = *(const bf16x8*)(kb0 + quad * 8);
        bf16x8 kf01 = *(const bf16x8*)(kb0 + 32 + quad * 8);
        bf16x8 kf10 = *(const bf16x8*)(kb1 + quad * 8);
        bf16x8 kf11 = *(const bf16x8*)(kb1 + 32 + quad * 8);

        f32x4 S0 = {0,0,0,0}, S1 = {0,0,0,0};
        S0 = __builtin_amdgcn_mfma_f32_16x16x32_bf16(qa0, kf00, S0, 0, 0, 0);
        S0 = __builtin_amdgcn_mfma_f32_16x16x32_bf16(qa1, kf01, S0, 0, 0, 0);
        S1 = __builtin_amdgcn_mfma_f32_16x16x32_bf16(qa0, kf10, S1, 0, 0, 0);
        S1 = __builtin_amdgcn_mfma_f32_16x16x32_bf16(qa1, kf11, S1, 0, 0, 0);

        float s0[4], s1[4], tmax[4];
#pragma unroll
        for (int r = 0; r < 4; ++r) {
            const int i  = q0 + quad * 4 + r;
            const int ja = j0 + col;
            const int jb = j0 + 16 + col;
            s0[r] = (ja <= i) ? S0[r] * scale + slope * (float)(i - ja) : -1e30f;
            s1[r] = (jb <= i) ? S1[r] * scale + slope * (float)(i - jb) : -1e30f;
            tmax[r] = fmaxf(s0[r], s1[r]);
        }
#pragma unroll
        for (int off = 1; off < 16; off <<= 1) {
#pragma unroll
            for (int r = 0; r < 4; ++r)
                tmax[r] = fmaxf(tmax[r], __shfl_xor(tmax[r], off));
        }
        float p0[4], p1[4];
#pragma unroll
        for (int r = 0; r < 4; ++r) {
            const float mn    = fmaxf(m_r[r], tmax[r]);
            const float alpha = __expf(m_r[r] - mn);
            m_r[r] = mn;
            p0[r] = __expf(s0[r] - mn);
            p1[r] = __expf(s1[r] - mn);
            float ts = p0[r] + p1[r];
#pragma unroll
            for (int off = 1; off < 16; off <<= 1) ts += __shfl_xor(ts, off);
            l_r[r] = l_r[r] * alpha + ts;
            O0[r] *= alpha; O1[r] *= alpha; O2[r] *= alpha; O3[r] *= alpha;
        }

#pragma unroll
        for (int r = 0; r < 4; ++r) {
            P[(quad * 4 + r) * 32 + col]      = f2bf(p0[r]);
            P[(quad * 4 + r) * 32 + 16 + col] = f2bf(p1[r]);
        }
        __asm__ volatile("s_waitcnt lgkmcnt(0)" ::: "memory");
        bf16x8 pa = *(bf16x8*)&P[col * 32 + quad * 8];
        __asm__ volatile("" ::: "memory");

        {
            bf16x8 vf0 = *(const bf16x8*)(vtb + (size_t)(0 * 16 + col) * SEQ + j0 + quad * 8);
            bf16x8 vf1 = *(const bf16x8*)(vtb + (size_t)(1 * 16 + col) * SEQ + j0 + quad * 8);
            bf16x8 vf2 = *(const bf16x8*)(vtb + (size_t)(2 * 16 + col) * SEQ + j0 + quad * 8);
            bf16x8 vf3 = *(const bf16x8*)(vtb + (size_t)(3 * 16 + col) * SEQ + j0 + quad * 8);
            O0 = __builtin_amdgcn_mfma_f32_16x16x32_bf16(pa, vf0, O0, 0, 0, 0);
            O1 = __builtin_amdgcn_mfma_f32_16x16x32_bf16(pa, vf1, O1, 0, 0, 0);
            O2 = __builtin_amdgcn_mfma_f32_16x16x32_bf16(pa, vf2, O2, 0, 0, 0);
            O3 = __builtin_amdgcn_mfma_f32_16x16x32_bf16(pa, vf3, O3, 0, 0, 0);
        }
    }

#pragma unroll
    for (int r = 0; r < 4; ++r) {
        const float inv = 1.f / l_r[r];
        const int row = q0 + quad * 4 + r;
        short* op = out + (size_t)(b * SEQ + row) * NEMBD + h * HDIM;
        op[col]      = f2bf(O0[r] * inv);
        op[16 + col] = f2bf(O1[r] * inv);
        op[32 + col] = f2bf(O2[r] * inv);
        op[48 + col] = f2bf(O3[r] * inv);
    }
}

// ---------------------------------------------------------------------------
extern "C" void kernel_launch(void* const* d_in, const int* in_sizes, int n_in,
                              void* d_out, int out_size, void* d_ws, size_t ws_size,
                              hipStream_t stream) {
    const float* x      = (const float*)d_in[0];   // [4096, 1024]
    const float* w_qkv  = (const float*)d_in[1];   // [1024, 3072]
    const float* w_proj = (const float*)d_in[2];   // [1024, 1024]
    float* out = (float*)d_out;                    // [4096, 1024] fp32

    // workspace layout (bf16 shorts): 50.4 MB total (ws held >= 67 MB in R1)
    short* xb    = (short*)d_ws;                         // [4096,1024]
    short* wqt   = xb   + (size_t)MROWS * NEMBD;         // [3072,1024] (B^T)
    short* wpt   = wqt  + (size_t)C3 * NEMBD;            // [1024,1024] (B^T)
    short* qkvb  = wpt  + (size_t)NEMBD * NEMBD;         // [4096,3072]
    short* attnb = qkvb + (size_t)MROWS * C3;            // [4096,1024]
    // bf16 V^T (8.4 MB) lives in d_out — free until proj GEMM writes it
    short* vt = (short*)d_out;

    // 1) converts
    conv_x<<<dim3(MROWS * NEMBD / (256 * 8)), 256, 0, stream>>>(x, xb, MROWS * NEMBD);
    conv_wt<<<dim3(C3 / 64, NEMBD / 64), 256, 0, stream>>>(w_qkv, wqt, NEMBD, C3);
    conv_wt<<<dim3(NEMBD / 64, NEMBD / 64), 256, 0, stream>>>(w_proj, wpt, NEMBD, NEMBD);
    // 2) qkv = x @ w_qkv  (bf16 MFMA)
    gemm_bt<short><<<dim3(C3 / 128, MROWS / 128), 256, 0, stream>>>(
        xb, wqt, qkvb, MROWS, C3, NEMBD);
    // 3) V -> V^T
    conv_vt<<<dim3(SEQ / 64, NHEAD, BATCH), 256, 0, stream>>>(qkvb, vt);
    // 4) flash attention
    attn_mfma<<<dim3(SEQ / 64, NHEAD, BATCH), 256, 0, stream>>>(qkvb, vt, attnb);
    // 5) out = attn @ w_proj (fp32 out)
    gemm_bt<float><<<dim3(NEMBD / 128, MROWS / 128), 256, 0, stream>>>(
        attnb, wpt, out, MROWS, NEMBD, NEMBD);
}

// Round 4
// 294.751 us; speedup vs baseline: 7.4283x; 1.2581x over previous
//
#include <hip/hip_runtime.h>
#include <hip/hip_bf16.h>
#include <math.h>

// Problem constants
#define BATCH   2
#define SEQ     2048
#define NHEAD   16
#define HDIM    64
#define NEMBD   1024
#define C3      (3*NEMBD)
#define MROWS   (BATCH*SEQ)   // 4096

typedef short bf16x8 __attribute__((ext_vector_type(8)));
typedef float f32x4  __attribute__((ext_vector_type(4)));

static __device__ __forceinline__ short f2bf(float x) {
    union { __hip_bfloat16 h; short s; } u;
    u.h = __float2bfloat16(x);
    return u.s;
}

static __device__ __forceinline__ void stc(float* p, float v) { *p = v; }
static __device__ __forceinline__ void stc(short* p, float v) { *p = f2bf(v); }

// async global->LDS, 16B per lane. LDS dest = wave-uniform base + lane*16.
static __device__ __forceinline__ void gl_lds16(const short* g, short* lds_base) {
    __builtin_amdgcn_global_load_lds(
        (const __attribute__((address_space(1))) unsigned int*)g,
        (__attribute__((address_space(3))) unsigned int*)lds_base,
        16, 0, 0);
}

// ---------------------------------------------------------------------------
// Elementwise fp32 -> bf16 convert (8 elems/thread).
// ---------------------------------------------------------------------------
__global__ __launch_bounds__(256) void conv_x(const float* __restrict__ in,
                                              short* __restrict__ out, int n) {
    const int i = (blockIdx.x * 256 + threadIdx.x) * 8;
    if (i >= n) return;
    float4 a = *(const float4*)(in + i);
    float4 b = *(const float4*)(in + i + 4);
    bf16x8 o;
    o[0] = f2bf(a.x); o[1] = f2bf(a.y); o[2] = f2bf(a.z); o[3] = f2bf(a.w);
    o[4] = f2bf(b.x); o[5] = f2bf(b.y); o[6] = f2bf(b.z); o[7] = f2bf(b.w);
    *(bf16x8*)(out + i) = o;
}

// ---------------------------------------------------------------------------
// Weight transpose + convert: in [K,N] fp32 row-major -> out [N,K] bf16.
// ---------------------------------------------------------------------------
__global__ __launch_bounds__(256) void conv_wt(const float* __restrict__ in,
                                               short* __restrict__ out,
                                               int K, int N) {
    __shared__ short tile[64][66];
    const int kt = blockIdx.y * 64, nt = blockIdx.x * 64;
    const int r  = threadIdx.x / 4;
    const int c0 = (threadIdx.x % 4) * 16;

    const float* src = in + (size_t)(kt + r) * N + nt + c0;
#pragma unroll
    for (int c = 0; c < 16; c += 4) {
        float4 v = *(const float4*)(src + c);
        tile[r][c0 + c + 0] = f2bf(v.x);
        tile[r][c0 + c + 1] = f2bf(v.y);
        tile[r][c0 + c + 2] = f2bf(v.z);
        tile[r][c0 + c + 3] = f2bf(v.w);
    }
    __syncthreads();

    const int nr  = threadIdx.x / 4;
    const int k0c = (threadIdx.x % 4) * 16;
    bf16x8 o0, o1;
#pragma unroll
    for (int k = 0; k < 8; ++k) o0[k] = tile[k0c + k][nr];
#pragma unroll
    for (int k = 0; k < 8; ++k) o1[k] = tile[k0c + 8 + k][nr];
    short* dst = out + (size_t)(nt + nr) * K + kt + k0c;
    *(bf16x8*)dst       = o0;
    *(bf16x8*)(dst + 8) = o1;
}

// ---------------------------------------------------------------------------
// bf16 MFMA GEMM (m97 structure): C = A @ B, A [M,K], BT [N,K] bf16.
// ---------------------------------------------------------------------------
template <typename OT>
__global__ __launch_bounds__(256) void gemm_bt(const short* __restrict__ A,
                                               const short* __restrict__ BT,
                                               OT* __restrict__ C,
                                               int M, int N, int K) {
    __shared__ short As[128 * 32];
    __shared__ short Bs[128 * 32];

    const int tid  = threadIdx.x;
    const int wave = tid >> 6;
    const int lane = tid & 63;
    const int quad = lane >> 4;
    const int col  = lane & 15;
    const int m0 = blockIdx.y * 128;
    const int n0 = blockIdx.x * 128;
    const int mq = (wave >> 1) * 64;
    const int nq = (wave & 1) * 64;

    f32x4 acc[4][4] = {};

    const int cA  = wave * 64 + lane;
    const int cA1 = cA + 256;

    for (int k0 = 0; k0 < K; k0 += 32) {
        if (k0) __syncthreads();
        gl_lds16(A + (size_t)(m0 + (cA  >> 2)) * K + k0 + (cA  & 3) * 8,
                 &As[wave * 512]);
        gl_lds16(A + (size_t)(m0 + (cA1 >> 2)) * K + k0 + (cA1 & 3) * 8,
                 &As[2048 + wave * 512]);
        gl_lds16(BT + (size_t)(n0 + (cA  >> 2)) * K + k0 + (cA  & 3) * 8,
                 &Bs[wave * 512]);
        gl_lds16(BT + (size_t)(n0 + (cA1 >> 2)) * K + k0 + (cA1 & 3) * 8,
                 &Bs[2048 + wave * 512]);
        __syncthreads();

        bf16x8 af[4], bfr[4];
#pragma unroll
        for (int mt = 0; mt < 4; ++mt)
            af[mt] = *(const bf16x8*)&As[(mq + mt * 16 + col) * 32 + quad * 8];
#pragma unroll
        for (int nt = 0; nt < 4; ++nt)
            bfr[nt] = *(const bf16x8*)&Bs[(nq + nt * 16 + col) * 32 + quad * 8];
#pragma unroll
        for (int mt = 0; mt < 4; ++mt)
#pragma unroll
            for (int nt = 0; nt < 4; ++nt)
                acc[mt][nt] = __builtin_amdgcn_mfma_f32_16x16x32_bf16(
                    af[mt], bfr[nt], acc[mt][nt], 0, 0, 0);
    }

#pragma unroll
    for (int mt = 0; mt < 4; ++mt)
#pragma unroll
        for (int r = 0; r < 4; ++r) {
            const int row = m0 + mq + mt * 16 + quad * 4 + r;
            OT* cp = C + (size_t)row * N + n0 + nq + col;
#pragma unroll
            for (int nt = 0; nt < 4; ++nt)
                stc(cp + nt * 16, acc[mt][nt][r]);
        }
}

// ---------------------------------------------------------------------------
// V transpose: qkvb bf16 [B*T,3072] (v at 2048+h*64) -> vt [B*H][64][2048]
// ---------------------------------------------------------------------------
__global__ __launch_bounds__(256) void conv_vt(const short* __restrict__ qkvb,
                                               short* __restrict__ vt) {
    __shared__ short tile[64][66];
    const int b = blockIdx.z, h = blockIdx.y, t0 = blockIdx.x * 64;
    const int tt = threadIdx.x / 4;
    const int c0 = (threadIdx.x % 4) * 16;

    const short* src = qkvb + (size_t)(b * SEQ + t0 + tt) * C3 + 2 * NEMBD + h * HDIM + c0;
    bf16x8 v0 = *(const bf16x8*)src;
    bf16x8 v1 = *(const bf16x8*)(src + 8);
#pragma unroll
    for (int k = 0; k < 8; ++k) tile[tt][c0 + k]     = v0[k];
#pragma unroll
    for (int k = 0; k < 8; ++k) tile[tt][c0 + 8 + k] = v1[k];
    __syncthreads();

    const int d  = threadIdx.x / 4;
    const int tp = (threadIdx.x % 4) * 16;
    bf16x8 o0, o1;
#pragma unroll
    for (int k = 0; k < 8; ++k) o0[k] = tile[tp + k][d];
#pragma unroll
    for (int k = 0; k < 8; ++k) o1[k] = tile[tp + 8 + k][d];
    short* dst = vt + ((size_t)(b * NHEAD + h) * HDIM + d) * SEQ + t0 + tp;
    *(bf16x8*)dst       = o0;
    *(bf16x8*)(dst + 8) = o1;
}

// ---------------------------------------------------------------------------
// MFMA flash attention, ALiBi (+slope*(i-j)), causal, FIXED-MAX softmax.
// Key insight: bias is monotone decreasing in j, so m_i = slope*i bounds all
// scores up to qk noise (|qk*scale| <~ 5). p = exp2(qk*scale2 - slope2*j)
// -> no per-tile max reduction, no O/l rescale, no shuffles in the loop.
// One wave per block (64 thr), 16-query tile, 64-key tiles, K prefetch.
// ---------------------------------------------------------------------------
__global__ __launch_bounds__(64) void attn_mfma(const short* __restrict__ qkvb,
                                                const short* __restrict__ vt,
                                                short* __restrict__ out) {
    __shared__ short P[16 * 64];   // 2 KB

    const int lane = threadIdx.x;
    const int quad = lane >> 4;
    const int col  = lane & 15;
    const int b = blockIdx.z, h = blockIdx.y;
    // spread work across co-resident blocks (ids differing by 256 share x)
    const int x  = (blockIdx.x + 8 * blockIdx.y + 4 * blockIdx.z) & 127;
    const int q0 = x * 16;

    const float LOG2E  = 1.4426950408889634f;
    const float scale2 = 0.125f * LOG2E;
    const float slope2 = exp2f(-0.5f * (float)(h + 1)) * LOG2E;

    const short* qbase = qkvb + (size_t)(b * SEQ + q0 + col) * C3 + h * HDIM;
    const bf16x8 qa0 = *(const bf16x8*)(qbase + quad * 8);
    const bf16x8 qa1 = *(const bf16x8*)(qbase + 32 + quad * 8);

    f32x4 O0 = {0,0,0,0}, O1 = {0,0,0,0}, O2 = {0,0,0,0}, O3 = {0,0,0,0};
    float lsum[4] = {0.f, 0.f, 0.f, 0.f};

    const short* kb_base = qkvb + (size_t)(b * SEQ) * C3 + NEMBD + h * HDIM;
    const short* vtb     = vt + (size_t)(b * NHEAD + h) * HDIM * SEQ;

    const int t_full = q0 >> 6;   // full (unmasked) 64-key tiles

    // preload K fragments for tile 0: rows g*16+col, dims quad*8 (+0/+32)
    bf16x8 kf[8];
#pragma unroll
    for (int g = 0; g < 4; ++g) {
        const short* kr = kb_base + (size_t)(g * 16 + col) * C3;
        kf[2 * g]     = *(const bf16x8*)(kr + quad * 8);
        kf[2 * g + 1] = *(const bf16x8*)(kr + 32 + quad * 8);
    }

    for (int t = 0; t < t_full; ++t) {
        const int j0 = t * 64;

        // V B-fragments (independent of S -> issue early)
        bf16x8 vf[8];
#pragma unroll
        for (int c = 0; c < 4; ++c) {
            const short* vr = vtb + (size_t)(c * 16 + col) * SEQ + j0 + quad * 8;
            vf[2 * c]     = *(const bf16x8*)vr;
            vf[2 * c + 1] = *(const bf16x8*)(vr + 32);
        }

        // S = Q @ K^T (keys j0 .. j0+63)
        f32x4 S[4];
#pragma unroll
        for (int g = 0; g < 4; ++g) {
            f32x4 s = {0, 0, 0, 0};
            s = __builtin_amdgcn_mfma_f32_16x16x32_bf16(qa0, kf[2 * g], s, 0, 0, 0);
            s = __builtin_amdgcn_mfma_f32_16x16x32_bf16(qa1, kf[2 * g + 1], s, 0, 0, 0);
            S[g] = s;
        }

        // prefetch next tile's K (t_full*64+63 <= 2047, always in-bounds)
#pragma unroll
        for (int g = 0; g < 4; ++g) {
            const short* kr = kb_base + (size_t)(j0 + 64 + g * 16 + col) * C3;
            kf[2 * g]     = *(const bf16x8*)(kr + quad * 8);
            kf[2 * g + 1] = *(const bf16x8*)(kr + 32 + quad * 8);
        }

        // p = exp2(S*scale2 - slope2*j); no mask needed (all keys <= q0-1 < i)
        const float cbase = -slope2 * (float)(j0 + col);
        const float d16   = -slope2 * 16.0f;
        float p[4][4];
#pragma unroll
        for (int g = 0; g < 4; ++g) {
            const float cg = cbase + d16 * (float)g;
#pragma unroll
            for (int r = 0; r < 4; ++r)
                p[g][r] = exp2f(S[g][r] * scale2 + cg);
        }
#pragma unroll
        for (int r = 0; r < 4; ++r)
            lsum[r] += (p[0][r] + p[1][r]) + (p[2][r] + p[3][r]);

        // P (C-layout) -> LDS [q][k] -> A-layout fragments
#pragma unroll
        for (int g = 0; g < 4; ++g)
#pragma unroll
            for (int r = 0; r < 4; ++r)
                P[(quad * 4 + r) * 64 + g * 16 + col] = f2bf(p[g][r]);
        __asm__ volatile("s_waitcnt lgkmcnt(0)" ::: "memory");
        bf16x8 pa0 = *(bf16x8*)&P[col * 64 + quad * 8];
        bf16x8 pa1 = *(bf16x8*)&P[col * 64 + 32 + quad * 8];
        __asm__ volatile("" ::: "memory");

        O0 = __builtin_amdgcn_mfma_f32_16x16x32_bf16(pa0, vf[0], O0, 0, 0, 0);
        O0 = __builtin_amdgcn_mfma_f32_16x16x32_bf16(pa1, vf[1], O0, 0, 0, 0);
        O1 = __builtin_amdgcn_mfma_f32_16x16x32_bf16(pa0, vf[2], O1, 0, 0, 0);
        O1 = __builtin_amdgcn_mfma_f32_16x16x32_bf16(pa1, vf[3], O1, 0, 0, 0);
        O2 = __builtin_amdgcn_mfma_f32_16x16x32_bf16(pa0, vf[4], O2, 0, 0, 0);
        O2 = __builtin_amdgcn_mfma_f32_16x16x32_bf16(pa1, vf[5], O2, 0, 0, 0);
        O3 = __builtin_amdgcn_mfma_f32_16x16x32_bf16(pa0, vf[6], O3, 0, 0, 0);
        O3 = __builtin_amdgcn_mfma_f32_16x16x32_bf16(pa1, vf[7], O3, 0, 0, 0);
    }

    // masked tail tile (keys t_full*64 .. +63; kf already holds it)
    {
        const int j0 = t_full * 64;
        bf16x8 vf[8];
#pragma unroll
        for (int c = 0; c < 4; ++c) {
            const short* vr = vtb + (size_t)(c * 16 + col) * SEQ + j0 + quad * 8;
            vf[2 * c]     = *(const bf16x8*)vr;
            vf[2 * c + 1] = *(const bf16x8*)(vr + 32);
        }
        f32x4 S[4];
#pragma unroll
        for (int g = 0; g < 4; ++g) {
            f32x4 s = {0, 0, 0, 0};
            s = __builtin_amdgcn_mfma_f32_16x16x32_bf16(qa0, kf[2 * g], s, 0, 0, 0);
            s = __builtin_amdgcn_mfma_f32_16x16x32_bf16(qa1, kf[2 * g + 1], s, 0, 0, 0);
            S[g] = s;
        }
        const float cbase = -slope2 * (float)(j0 + col);
        const float d16   = -slope2 * 16.0f;
        float p[4][4];
#pragma unroll
        for (int g = 0; g < 4; ++g) {
            const float cg = cbase + d16 * (float)g;
            const int   jg = j0 + g * 16 + col;
#pragma unroll
            for (int r = 0; r < 4; ++r) {
                const int i = q0 + quad * 4 + r;
                p[g][r] = (jg <= i) ? exp2f(S[g][r] * scale2 + cg) : 0.f;
            }
        }
#pragma unroll
        for (int r = 0; r < 4; ++r)
            lsum[r] += (p[0][r] + p[1][r]) + (p[2][r] + p[3][r]);
#pragma unroll
        for (int g = 0; g < 4; ++g)
#pragma unroll
            for (int r = 0; r < 4; ++r)
                P[(quad * 4 + r) * 64 + g * 16 + col] = f2bf(p[g][r]);
        __asm__ volatile("s_waitcnt lgkmcnt(0)" ::: "memory");
        bf16x8 pa0 = *(bf16x8*)&P[col * 64 + quad * 8];
        bf16x8 pa1 = *(bf16x8*)&P[col * 64 + 32 + quad * 8];
        __asm__ volatile("" ::: "memory");
        O0 = __builtin_amdgcn_mfma_f32_16x16x32_bf16(pa0, vf[0], O0, 0, 0, 0);
        O0 = __builtin_amdgcn_mfma_f32_16x16x32_bf16(pa1, vf[1], O0, 0, 0, 0);
        O1 = __builtin_amdgcn_mfma_f32_16x16x32_bf16(pa0, vf[2], O1, 0, 0, 0);
        O1 = __builtin_amdgcn_mfma_f32_16x16x32_bf16(pa1, vf[3], O1, 0, 0, 0);
        O2 = __builtin_amdgcn_mfma_f32_16x16x32_bf16(pa0, vf[4], O2, 0, 0, 0);
        O2 = __builtin_amdgcn_mfma_f32_16x16x32_bf16(pa1, vf[5], O2, 0, 0, 0);
        O3 = __builtin_amdgcn_mfma_f32_16x16x32_bf16(pa0, vf[6], O3, 0, 0, 0);
        O3 = __builtin_amdgcn_mfma_f32_16x16x32_bf16(pa1, vf[7], O3, 0, 0, 0);
    }

    // final l reduction across the 16 key-columns (once, not per tile)
#pragma unroll
    for (int off = 1; off < 16; off <<= 1)
#pragma unroll
        for (int r = 0; r < 4; ++r)
            lsum[r] += __shfl_xor(lsum[r], off);

#pragma unroll
    for (int r = 0; r < 4; ++r) {
        const float inv = 1.f / lsum[r];
        const int row = q0 + quad * 4 + r;
        short* op = out + (size_t)(b * SEQ + row) * NEMBD + h * HDIM;
        op[col]      = f2bf(O0[r] * inv);
        op[16 + col] = f2bf(O1[r] * inv);
        op[32 + col] = f2bf(O2[r] * inv);
        op[48 + col] = f2bf(O3[r] * inv);
    }
}

// ---------------------------------------------------------------------------
extern "C" void kernel_launch(void* const* d_in, const int* in_sizes, int n_in,
                              void* d_out, int out_size, void* d_ws, size_t ws_size,
                              hipStream_t stream) {
    const float* x      = (const float*)d_in[0];
    const float* w_qkv  = (const float*)d_in[1];
    const float* w_proj = (const float*)d_in[2];
    float* out = (float*)d_out;

    short* xb    = (short*)d_ws;
    short* wqt   = xb   + (size_t)MROWS * NEMBD;
    short* wpt   = wqt  + (size_t)C3 * NEMBD;
    short* qkvb  = wpt  + (size_t)NEMBD * NEMBD;
    short* attnb = qkvb + (size_t)MROWS * C3;
    short* vt = (short*)d_out;   // free until proj GEMM writes d_out

    conv_x<<<dim3(MROWS * NEMBD / (256 * 8)), 256, 0, stream>>>(x, xb, MROWS * NEMBD);
    conv_wt<<<dim3(C3 / 64, NEMBD / 64), 256, 0, stream>>>(w_qkv, wqt, NEMBD, C3);
    conv_wt<<<dim3(NEMBD / 64, NEMBD / 64), 256, 0, stream>>>(w_proj, wpt, NEMBD, NEMBD);
    gemm_bt<short><<<dim3(C3 / 128, MROWS / 128), 256, 0, stream>>>(
        xb, wqt, qkvb, MROWS, C3, NEMBD);
    conv_vt<<<dim3(SEQ / 64, NHEAD, BATCH), 256, 0, stream>>>(qkvb, vt);
    attn_mfma<<<dim3(SEQ / 16, NHEAD, BATCH), 64, 0, stream>>>(qkvb, vt, attnb);
    gemm_bt<float><<<dim3(NEMBD / 128, MROWS / 128), 256, 0, stream>>>(
        attnb, wpt, out, MROWS, NEMBD, NEMBD);
}

// Round 5
// 206.999 us; speedup vs baseline: 10.5773x; 1.4239x over previous
//
#include <hip/hip_runtime.h>
#include <hip/hip_bf16.h>
#include <math.h>

// Problem constants
#define BATCH   2
#define SEQ     2048
#define NHEAD   16
#define HDIM    64
#define NEMBD   1024
#define C3      (3*NEMBD)
#define MROWS   (BATCH*SEQ)   // 4096

typedef short bf16x8 __attribute__((ext_vector_type(8)));
typedef float f32x4  __attribute__((ext_vector_type(4)));

static __device__ __forceinline__ short f2bf(float x) {
    union { __hip_bfloat16 h; short s; } u;
    u.h = __float2bfloat16(x);
    return u.s;
}

static __device__ __forceinline__ void stc(float* p, float v) { *p = v; }
static __device__ __forceinline__ void stc(short* p, float v) { *p = f2bf(v); }

// async global->LDS, 16B per lane. LDS dest = wave-uniform base + lane*16.
static __device__ __forceinline__ void gl_lds16(const short* g, short* lds_base) {
    __builtin_amdgcn_global_load_lds(
        (const __attribute__((address_space(1))) unsigned int*)g,
        (__attribute__((address_space(3))) unsigned int*)lds_base,
        16, 0, 0);
}

// ---------------------------------------------------------------------------
// Elementwise fp32 -> bf16 convert (8 elems/thread).
// ---------------------------------------------------------------------------
__global__ __launch_bounds__(256) void conv_x(const float* __restrict__ in,
                                              short* __restrict__ out, int n) {
    const int i = (blockIdx.x * 256 + threadIdx.x) * 8;
    if (i >= n) return;
    float4 a = *(const float4*)(in + i);
    float4 b = *(const float4*)(in + i + 4);
    bf16x8 o;
    o[0] = f2bf(a.x); o[1] = f2bf(a.y); o[2] = f2bf(a.z); o[3] = f2bf(a.w);
    o[4] = f2bf(b.x); o[5] = f2bf(b.y); o[6] = f2bf(b.z); o[7] = f2bf(b.w);
    *(bf16x8*)(out + i) = o;
}

// ---------------------------------------------------------------------------
// Weight transpose + convert: in [K,N] fp32 row-major -> out [N,K] bf16.
// ---------------------------------------------------------------------------
__global__ __launch_bounds__(256) void conv_wt(const float* __restrict__ in,
                                               short* __restrict__ out,
                                               int K, int N) {
    __shared__ short tile[64][66];
    const int kt = blockIdx.y * 64, nt = blockIdx.x * 64;
    const int r  = threadIdx.x / 4;
    const int c0 = (threadIdx.x % 4) * 16;

    const float* src = in + (size_t)(kt + r) * N + nt + c0;
#pragma unroll
    for (int c = 0; c < 16; c += 4) {
        float4 v = *(const float4*)(src + c);
        tile[r][c0 + c + 0] = f2bf(v.x);
        tile[r][c0 + c + 1] = f2bf(v.y);
        tile[r][c0 + c + 2] = f2bf(v.z);
        tile[r][c0 + c + 3] = f2bf(v.w);
    }
    __syncthreads();

    const int nr  = threadIdx.x / 4;
    const int k0c = (threadIdx.x % 4) * 16;
    bf16x8 o0, o1;
#pragma unroll
    for (int k = 0; k < 8; ++k) o0[k] = tile[k0c + k][nr];
#pragma unroll
    for (int k = 0; k < 8; ++k) o1[k] = tile[k0c + 8 + k][nr];
    short* dst = out + (size_t)(nt + nr) * K + kt + k0c;
    *(bf16x8*)dst       = o0;
    *(bf16x8*)(dst + 8) = o1;
}

// ---------------------------------------------------------------------------
// bf16 MFMA GEMM (m97 structure): C = A @ B, A [M,K], BT [N,K] bf16.
// ---------------------------------------------------------------------------
template <typename OT>
__global__ __launch_bounds__(256) void gemm_bt(const short* __restrict__ A,
                                               const short* __restrict__ BT,
                                               OT* __restrict__ C,
                                               int M, int N, int K) {
    __shared__ short As[128 * 32];
    __shared__ short Bs[128 * 32];

    const int tid  = threadIdx.x;
    const int wave = tid >> 6;
    const int lane = tid & 63;
    const int quad = lane >> 4;
    const int col  = lane & 15;
    const int m0 = blockIdx.y * 128;
    const int n0 = blockIdx.x * 128;
    const int mq = (wave >> 1) * 64;
    const int nq = (wave & 1) * 64;

    f32x4 acc[4][4] = {};

    const int cA  = wave * 64 + lane;
    const int cA1 = cA + 256;

    for (int k0 = 0; k0 < K; k0 += 32) {
        if (k0) __syncthreads();
        gl_lds16(A + (size_t)(m0 + (cA  >> 2)) * K + k0 + (cA  & 3) * 8,
                 &As[wave * 512]);
        gl_lds16(A + (size_t)(m0 + (cA1 >> 2)) * K + k0 + (cA1 & 3) * 8,
                 &As[2048 + wave * 512]);
        gl_lds16(BT + (size_t)(n0 + (cA  >> 2)) * K + k0 + (cA  & 3) * 8,
                 &Bs[wave * 512]);
        gl_lds16(BT + (size_t)(n0 + (cA1 >> 2)) * K + k0 + (cA1 & 3) * 8,
                 &Bs[2048 + wave * 512]);
        __syncthreads();

        bf16x8 af[4], bfr[4];
#pragma unroll
        for (int mt = 0; mt < 4; ++mt)
            af[mt] = *(const bf16x8*)&As[(mq + mt * 16 + col) * 32 + quad * 8];
#pragma unroll
        for (int nt = 0; nt < 4; ++nt)
            bfr[nt] = *(const bf16x8*)&Bs[(nq + nt * 16 + col) * 32 + quad * 8];
#pragma unroll
        for (int mt = 0; mt < 4; ++mt)
#pragma unroll
            for (int nt = 0; nt < 4; ++nt)
                acc[mt][nt] = __builtin_amdgcn_mfma_f32_16x16x32_bf16(
                    af[mt], bfr[nt], acc[mt][nt], 0, 0, 0);
    }

#pragma unroll
    for (int mt = 0; mt < 4; ++mt)
#pragma unroll
        for (int r = 0; r < 4; ++r) {
            const int row = m0 + mq + mt * 16 + quad * 4 + r;
            OT* cp = C + (size_t)row * N + n0 + nq + col;
#pragma unroll
            for (int nt = 0; nt < 4; ++nt)
                stc(cp + nt * 16, acc[mt][nt][r]);
        }
}

// ---------------------------------------------------------------------------
// V transpose: qkvb bf16 [B*T,3072] (v at 2048+h*64) -> vt [B*H][64][2048]
// ---------------------------------------------------------------------------
__global__ __launch_bounds__(256) void conv_vt(const short* __restrict__ qkvb,
                                               short* __restrict__ vt) {
    __shared__ short tile[64][66];
    const int b = blockIdx.z, h = blockIdx.y, t0 = blockIdx.x * 64;
    const int tt = threadIdx.x / 4;
    const int c0 = (threadIdx.x % 4) * 16;

    const short* src = qkvb + (size_t)(b * SEQ + t0 + tt) * C3 + 2 * NEMBD + h * HDIM + c0;
    bf16x8 v0 = *(const bf16x8*)src;
    bf16x8 v1 = *(const bf16x8*)(src + 8);
#pragma unroll
    for (int k = 0; k < 8; ++k) tile[tt][c0 + k]     = v0[k];
#pragma unroll
    for (int k = 0; k < 8; ++k) tile[tt][c0 + 8 + k] = v1[k];
    __syncthreads();

    const int d  = threadIdx.x / 4;
    const int tp = (threadIdx.x % 4) * 16;
    bf16x8 o0, o1;
#pragma unroll
    for (int k = 0; k < 8; ++k) o0[k] = tile[tp + k][d];
#pragma unroll
    for (int k = 0; k < 8; ++k) o1[k] = tile[tp + 8 + k][d];
    short* dst = vt + ((size_t)(b * NHEAD + h) * HDIM + d) * SEQ + t0 + tp;
    *(bf16x8*)dst       = o0;
    *(bf16x8*)(dst + 8) = o1;
}

// ---------------------------------------------------------------------------
// MFMA flash attention v2: ALiBi (+slope*(i-j)), causal, fixed-max softmax
//   p = exp2(qk*scale2 - slope2*j)   (reference max m_i = slope*i)
// Block = 256 thr (4 waves) = 64 queries; K/V 64-key tiles staged to LDS via
// global_load_lds, double-buffered, SHARED by all 4 waves (4x traffic cut).
// ALiBi truncation: keys with slope2*j > 56 contribute < 2^-39 relative ->
// skip whole tiles (h0: 1 tile, h8: 14, h12+: all). Heavy blocks launch first.
// LDS regions are 64x32-short quarters so ds_read_b128 matches the m97 bank
// pattern. P transpose path identical to R4 (known correct).
// ---------------------------------------------------------------------------
__global__ __launch_bounds__(256) void attn_mfma(const short* __restrict__ qkvb,
                                                 const short* __restrict__ vt,
                                                 short* __restrict__ out) {
    // [buf][region][64 rows * 32 shorts]; regions: 0=Klo 1=Khi 2=Vlo 3=Vhi
    __shared__ short KV[2][4][2048];   // 32 KB
    __shared__ short P_lds[4][16 * 64];  // 8 KB, per-wave

    const int tid  = threadIdx.x;
    const int wave = tid >> 6;
    const int lane = tid & 63;
    const int quad = lane >> 4;
    const int col  = lane & 15;
    const int b = blockIdx.z, h = blockIdx.y;
    const int X = 31 - (int)blockIdx.x;       // heavy (large X) dispatched first
    const int q0 = X * 64 + wave * 16;        // this wave's 16-query tile

    const float LOG2E  = 1.4426950408889634f;
    const float scale2 = 0.125f * LOG2E;
    const float slope2 = exp2f(-0.5f * (float)(h + 1)) * LOG2E;

    // tile count: causal need X+1; ALiBi cut: slope2*j <= 56 relevant
    const int Tneed = X + 1;
    const int Tcut  = ((int)(56.0f / slope2) >> 6) + 1;
    const int T     = Tneed < Tcut ? Tneed : Tcut;
    const bool masked_last = (T == Tneed);

    const short* kb  = qkvb + (size_t)(b * SEQ) * C3 + NEMBD + h * HDIM;
    const short* vtb = vt + (size_t)(b * NHEAD + h) * HDIM * SEQ;

    // Q A-fragments: rows q0+col, dims quad*8 (+0 / +32)
    const short* qbase = qkvb + (size_t)(b * SEQ + q0 + col) * C3 + h * HDIM;
    const bf16x8 qa0 = *(const bf16x8*)(qbase + quad * 8);
    const bf16x8 qa1 = *(const bf16x8*)(qbase + 32 + quad * 8);

    f32x4 O0 = {0,0,0,0}, O1 = {0,0,0,0}, O2 = {0,0,0,0}, O3 = {0,0,0,0};
    float lsum[4] = {0.f, 0.f, 0.f, 0.f};
    short* P = P_lds[wave];

    // stage tile t into buffer buf: thread handles chunk c=tid in each region.
    // chunk c: row = c>>2, 8-elem group = (c&3)*8; LDS offset = c*8 shorts
    // (= wave*512 base + lane*16B, the required lane-linear order).
#define STAGE(t_, buf_) do {                                                  \
        const int jj = (t_) * 64;                                             \
        const int row = tid >> 2, g8 = (tid & 3) * 8;                         \
        gl_lds16(kb  + (size_t)(jj + row) * C3 + g8,       &KV[buf_][0][wave * 512]); \
        gl_lds16(kb  + (size_t)(jj + row) * C3 + 32 + g8,  &KV[buf_][1][wave * 512]); \
        gl_lds16(vtb + (size_t)row * SEQ + jj + g8,        &KV[buf_][2][wave * 512]); \
        gl_lds16(vtb + (size_t)row * SEQ + jj + 32 + g8,   &KV[buf_][3][wave * 512]); \
    } while (0)

    STAGE(0, 0);

    for (int t = 0; t < T; ++t) {
        const int buf = t & 1;
        __syncthreads();             // drains vmcnt -> buf ready; prev reads done
        if (t + 1 < T) STAGE(t + 1, buf ^ 1);

        const int j0 = t * 64;

        // K B-fragments from LDS: key g*16+col, dims quad*8 (lo/hi)
        f32x4 S[4];
#pragma unroll
        for (int g = 0; g < 4; ++g) {
            bf16x8 k0 = *(const bf16x8*)&KV[buf][0][(g * 16 + col) * 32 + quad * 8];
            bf16x8 k1 = *(const bf16x8*)&KV[buf][1][(g * 16 + col) * 32 + quad * 8];
            f32x4 s = {0, 0, 0, 0};
            s = __builtin_amdgcn_mfma_f32_16x16x32_bf16(qa0, k0, s, 0, 0, 0);
            s = __builtin_amdgcn_mfma_f32_16x16x32_bf16(qa1, k1, s, 0, 0, 0);
            S[g] = s;
        }

        // softmax weights p = exp2(S*scale2 - slope2*j)
        const float cbase = -slope2 * (float)(j0 + col);
        const float d16   = -slope2 * 16.0f;
        float p[4][4];
        if (masked_last && t == T - 1) {
#pragma unroll
            for (int g = 0; g < 4; ++g) {
                const float cg = cbase + d16 * (float)g;
                const int   jg = j0 + g * 16 + col;
#pragma unroll
                for (int r = 0; r < 4; ++r) {
                    const int i = q0 + quad * 4 + r;
                    p[g][r] = (jg <= i) ? exp2f(S[g][r] * scale2 + cg) : 0.f;
                }
            }
        } else {
#pragma unroll
            for (int g = 0; g < 4; ++g) {
                const float cg = cbase + d16 * (float)g;
#pragma unroll
                for (int r = 0; r < 4; ++r)
                    p[g][r] = exp2f(S[g][r] * scale2 + cg);
            }
        }
#pragma unroll
        for (int r = 0; r < 4; ++r)
            lsum[r] += (p[0][r] + p[1][r]) + (p[2][r] + p[3][r]);

        // P (C-layout) -> LDS [q][k] -> A-layout fragments (R4-verified path)
#pragma unroll
        for (int g = 0; g < 4; ++g)
#pragma unroll
            for (int r = 0; r < 4; ++r)
                P[(quad * 4 + r) * 64 + g * 16 + col] = f2bf(p[g][r]);
        __asm__ volatile("s_waitcnt lgkmcnt(0)" ::: "memory");
        bf16x8 pa0 = *(bf16x8*)&P[col * 64 + quad * 8];
        bf16x8 pa1 = *(bf16x8*)&P[col * 64 + 32 + quad * 8];
        __asm__ volatile("" ::: "memory");

        // O += P @ V: V^T B-fragments (dim c*16+col, keys quad*8, lo/hi)
        {
            bf16x8 vl0 = *(const bf16x8*)&KV[buf][2][(0 * 16 + col) * 32 + quad * 8];
            bf16x8 vh0 = *(const bf16x8*)&KV[buf][3][(0 * 16 + col) * 32 + quad * 8];
            O0 = __builtin_amdgcn_mfma_f32_16x16x32_bf16(pa0, vl0, O0, 0, 0, 0);
            O0 = __builtin_amdgcn_mfma_f32_16x16x32_bf16(pa1, vh0, O0, 0, 0, 0);
            bf16x8 vl1 = *(const bf16x8*)&KV[buf][2][(1 * 16 + col) * 32 + quad * 8];
            bf16x8 vh1 = *(const bf16x8*)&KV[buf][3][(1 * 16 + col) * 32 + quad * 8];
            O1 = __builtin_amdgcn_mfma_f32_16x16x32_bf16(pa0, vl1, O1, 0, 0, 0);
            O1 = __builtin_amdgcn_mfma_f32_16x16x32_bf16(pa1, vh1, O1, 0, 0, 0);
            bf16x8 vl2 = *(const bf16x8*)&KV[buf][2][(2 * 16 + col) * 32 + quad * 8];
            bf16x8 vh2 = *(const bf16x8*)&KV[buf][3][(2 * 16 + col) * 32 + quad * 8];
            O2 = __builtin_amdgcn_mfma_f32_16x16x32_bf16(pa0, vl2, O2, 0, 0, 0);
            O2 = __builtin_amdgcn_mfma_f32_16x16x32_bf16(pa1, vh2, O2, 0, 0, 0);
            bf16x8 vl3 = *(const bf16x8*)&KV[buf][2][(3 * 16 + col) * 32 + quad * 8];
            bf16x8 vh3 = *(const bf16x8*)&KV[buf][3][(3 * 16 + col) * 32 + quad * 8];
            O3 = __builtin_amdgcn_mfma_f32_16x16x32_bf16(pa0, vl3, O3, 0, 0, 0);
            O3 = __builtin_amdgcn_mfma_f32_16x16x32_bf16(pa1, vh3, O3, 0, 0, 0);
        }
    }
#undef STAGE

    // final l reduction across the 16 key-columns
#pragma unroll
    for (int off = 1; off < 16; off <<= 1)
#pragma unroll
        for (int r = 0; r < 4; ++r)
            lsum[r] += __shfl_xor(lsum[r], off);

#pragma unroll
    for (int r = 0; r < 4; ++r) {
        const float inv = 1.f / lsum[r];
        const int row = q0 + quad * 4 + r;
        short* op = out + (size_t)(b * SEQ + row) * NEMBD + h * HDIM;
        op[col]      = f2bf(O0[r] * inv);
        op[16 + col] = f2bf(O1[r] * inv);
        op[32 + col] = f2bf(O2[r] * inv);
        op[48 + col] = f2bf(O3[r] * inv);
    }
}

// ---------------------------------------------------------------------------
extern "C" void kernel_launch(void* const* d_in, const int* in_sizes, int n_in,
                              void* d_out, int out_size, void* d_ws, size_t ws_size,
                              hipStream_t stream) {
    const float* x      = (const float*)d_in[0];
    const float* w_qkv  = (const float*)d_in[1];
    const float* w_proj = (const float*)d_in[2];
    float* out = (float*)d_out;

    short* xb    = (short*)d_ws;
    short* wqt   = xb   + (size_t)MROWS * NEMBD;
    short* wpt   = wqt  + (size_t)C3 * NEMBD;
    short* qkvb  = wpt  + (size_t)NEMBD * NEMBD;
    short* attnb = qkvb + (size_t)MROWS * C3;
    short* vt = (short*)d_out;   // free until proj GEMM writes d_out

    conv_x<<<dim3(MROWS * NEMBD / (256 * 8)), 256, 0, stream>>>(x, xb, MROWS * NEMBD);
    conv_wt<<<dim3(C3 / 64, NEMBD / 64), 256, 0, stream>>>(w_qkv, wqt, NEMBD, C3);
    conv_wt<<<dim3(NEMBD / 64, NEMBD / 64), 256, 0, stream>>>(w_proj, wpt, NEMBD, NEMBD);
    gemm_bt<short><<<dim3(C3 / 128, MROWS / 128), 256, 0, stream>>>(
        xb, wqt, qkvb, MROWS, C3, NEMBD);
    conv_vt<<<dim3(SEQ / 64, NHEAD, BATCH), 256, 0, stream>>>(qkvb, vt);
    attn_mfma<<<dim3(SEQ / 64, NHEAD, BATCH), 256, 0, stream>>>(qkvb, vt, attnb);
    gemm_bt<float><<<dim3(NEMBD / 128, MROWS / 128), 256, 0, stream>>>(
        attnb, wpt, out, MROWS, NEMBD, NEMBD);
}